// Round 1
// baseline (158.965 us; speedup 1.0000x reference)
//
#include <hip/hip_runtime.h>

// RepulsionXTB: per-pair repulsion energy, segment-summed per molecule.
//
// Inputs (setup_inputs order, harness converts ints to int32):
//   d_in[0] element_idxs  int32  [M*A]   (M=2048, A=64 -> 131072)
//   d_in[1] neighbor_idxs int32  [2*P]   (P=8388608)
//   d_in[2] distances     f32    [P]
//   d_in[3] y_ab          f32    [16]
//   d_in[4] sqrt_alpha_ab f32    [16]
//   d_in[5] k_rep_ab      f32    [16]   (1.5 everywhere except [0,0]=1.0)
// Output: energies f32 [M]
//
// R4: counters showed latency-bound (VALU 15.8%, HBM 13%, VGPR=20 ->
// compiler fully serialized each pair's 3-deep LDS chain). Restructured
// into 8-pair phased super-groups: batch global loads, batch 16 pk reads,
// batch 8 tbl reads, branchless VALU, batch atomics. Branch removed via
// om=max(1-x^2,0) -> rcp(0)=+inf -> exp2(-inf)=0 outside cutoff.

#define AB_D 1.8897261258369282
#define L2E  1.4426950408889634f   // log2(e)

// ---------------- kernel 1: pack species to 2 bits/atom + zero output -------
__global__ __launch_bounds__(256) void pack_zero_kernel(
    const int* __restrict__ elem, int natoms, int nwords,
    unsigned* __restrict__ packed, float* __restrict__ out, int M)
{
    int g = blockIdx.x * blockDim.x + threadIdx.x;
    if (g < M) out[g] = 0.0f;
    if (packed != nullptr && g < nwords) {
        int base = g * 16;
        unsigned w = 0u;
        if (base + 16 <= natoms) {
            const int4* p = (const int4*)(elem + base);
            #pragma unroll
            for (int q = 0; q < 4; ++q) {
                int4 v = p[q];
                w |= ((unsigned)v.x & 3u) << (2 * (4 * q + 0));
                w |= ((unsigned)v.y & 3u) << (2 * (4 * q + 1));
                w |= ((unsigned)v.z & 3u) << (2 * (4 * q + 2));
                w |= ((unsigned)v.w & 3u) << (2 * (4 * q + 3));
            }
        } else {
            for (int j = 0; j < 16; ++j) {
                int a = base + j;
                unsigned s = (a < natoms) ? ((unsigned)elem[a] & 3u) : 0u;
                w |= s << (2 * j);
            }
        }
        packed[g] = w;
    }
}

// ---------------- kernel 2: main pair loop ----------------------------------
// LDS layout: [acc: M f32][tbl: 16 float2][pk: nwords u32]
__global__ __launch_bounds__(1024, 8) void rep_main_kernel(
    const int* __restrict__ nbr, const float* __restrict__ dist,
    const unsigned* __restrict__ packed_g,
    const float* __restrict__ y_ab, const float* __restrict__ sa_ab,
    const float* __restrict__ kr_ab,
    long long P, int M, int nwords, int ashift, int A,
    float* __restrict__ partials, float* __restrict__ out,
    int mode /*0 = write partial row, 1 = global atomics*/)
{
    extern __shared__ char smem[];
    float*  acc = (float*)smem;
    float2* tbl = (float2*)(smem + (size_t)M * 4);
    unsigned* pk = (unsigned*)(smem + (size_t)M * 4 + 16 * sizeof(float2));

    const int tid = threadIdx.x;
    const int nthr = blockDim.x;

    for (int m = tid; m < M; m += nthr) acc[m] = 0.0f;
    for (int w = tid; w < nwords; w += nthr) pk[w] = packed_g[w];
    if (tid < 16) {
        float sa = sa_ab[tid] * L2E;           // pre-scale for exp2
        if (kr_ab[tid] == 1.0f) sa = -sa;      // sign bit encodes kr==1 (H-H)
        tbl[tid] = make_float2(y_ab[tid], sa);
    }
    __syncthreads();

    const float ABf   = (float)AB_D;
    const float DMIN  = (float)(1e-7 * AB_D);
    const float RCINV = (float)(1.0 / (5.2 * AB_D));

    const int4*   nb04 = (const int4*)nbr;
    const int4*   nb14 = (const int4*)(nbr + P);
    const float4* dv4  = (const float4*)dist;

    // -------- main loop: 8-pair super-groups, phase-batched for ILP --------
    long long P8 = P >> 3;
    long long gstride = (long long)gridDim.x * nthr;
    for (long long g = (long long)blockIdx.x * nthr + tid; g < P8; g += gstride) {
        long long q = g << 1;
        // phase 0: global loads (6 x 16B, independent)
        int4   i0a = nb04[q];     int4   i0b = nb04[q + 1];
        int4   i1a = nb14[q];     int4   i1b = nb14[q + 1];
        float4 da  = dv4[q];      float4 db  = dv4[q + 1];

        unsigned a0[8] = {(unsigned)i0a.x,(unsigned)i0a.y,(unsigned)i0a.z,(unsigned)i0a.w,
                          (unsigned)i0b.x,(unsigned)i0b.y,(unsigned)i0b.z,(unsigned)i0b.w};
        unsigned a1[8] = {(unsigned)i1a.x,(unsigned)i1a.y,(unsigned)i1a.z,(unsigned)i1a.w,
                          (unsigned)i1b.x,(unsigned)i1b.y,(unsigned)i1b.z,(unsigned)i1b.w};
        float dr[8] = {da.x,da.y,da.z,da.w, db.x,db.y,db.z,db.w};

        // phase 1: species-word LDS reads (16 independent in flight)
        unsigned w0[8], w1[8];
        #pragma unroll
        for (int j = 0; j < 8; ++j) {
            w0[j] = pk[a0[j] >> 4];
            w1[j] = pk[a1[j] >> 4];
        }

        // phase 2: pair-table LDS reads (8 independent); a0/a1/w0/w1 die here
        float2   t[8];
        unsigned mol[8];
        #pragma unroll
        for (int j = 0; j < 8; ++j) {
            unsigned s0 = (w0[j] >> ((a0[j] & 15u) * 2u)) & 3u;
            unsigned s1 = (w1[j] >> ((a1[j] & 15u) * 2u)) & 3u;
            t[j] = tbl[s0 * 4u + s1];
            mol[j] = (ashift >= 0) ? (a0[j] >> ashift) : (a0[j] / (unsigned)A);
        }

        // phase 3: pure VALU, branchless (outside cutoff -> exp2(-inf) = 0)
        float rep[8];
        #pragma unroll
        for (int j = 0; j < 8; ++j) {
            float d   = fmaxf(dr[j] * ABf, DMIN);
            float x   = d * RCINV;
            float om  = fmaxf(fmaf(-x, x, 1.0f), 0.0f); // 0 outside cutoff
            float r   = __builtin_amdgcn_rcpf(om);      // +inf outside
            float e   = fmaf(-L2E, r, L2E);             // -inf outside
            float sq  = __builtin_amdgcn_sqrtf(d);
            float fac = (t[j].y < 0.0f) ? 1.0f : sq;    // kr==1 ? d : d^1.5
            float arg = fmaf(-fabsf(t[j].y), d * fac, e);
            float ex  = __builtin_amdgcn_exp2f(arg);
            rep[j] = t[j].x * __builtin_amdgcn_rcpf(d) * ex;
        }

        // phase 4: LDS atomics (fire-and-forget)
        #pragma unroll
        for (int j = 0; j < 8; ++j)
            atomicAdd(&acc[mol[j]], rep[j]);
    }

    // tail (P not divisible by 8) — handled by block 0 (empty for P=8.4M)
    long long tail0 = P8 << 3;
    if (blockIdx.x == 0) {
        const int* nb0 = nbr;
        const int* nb1 = nbr + P;
        for (long long p = tail0 + tid; p < P; p += nthr) {
            unsigned ua0 = (unsigned)nb0[p], ua1 = (unsigned)nb1[p];
            float d = fmaxf(dist[p] * ABf, DMIN);
            unsigned s0 = (pk[ua0 >> 4] >> ((ua0 & 15u) * 2u)) & 3u;
            unsigned s1 = (pk[ua1 >> 4] >> ((ua1 & 15u) * 2u)) & 3u;
            float2 t = tbl[s0 * 4u + s1];
            float x   = d * RCINV;
            float om  = fmaxf(fmaf(-x, x, 1.0f), 0.0f);
            float r   = __builtin_amdgcn_rcpf(om);
            float e   = fmaf(-L2E, r, L2E);
            float sq  = __builtin_amdgcn_sqrtf(d);
            float fac = (t.y < 0.0f) ? 1.0f : sq;
            float arg = fmaf(-fabsf(t.y), d * fac, e);
            float ex  = __builtin_amdgcn_exp2f(arg);
            float rep = t.x * __builtin_amdgcn_rcpf(d) * ex;
            unsigned mol = (ashift >= 0) ? (ua0 >> ashift) : (ua0 / (unsigned)A);
            atomicAdd(&acc[mol], rep);
        }
    }
    __syncthreads();

    if (mode == 0) {
        float* row = partials + (size_t)blockIdx.x * (size_t)M;
        for (int m = tid; m < M; m += nthr) row[m] = acc[m];
    } else {
        for (int m = tid; m < M; m += nthr) {
            float v = acc[m];
            if (v != 0.0f) atomicAdd(&out[m], v);
        }
    }
}

// ---------------- kernel 3: column-sum the partial rows ---------------------
__global__ __launch_bounds__(256) void reduce_kernel(
    const float* __restrict__ partials, float* __restrict__ out,
    int M, int nblk, int rows_per)
{
    int m = blockIdx.x * blockDim.x + threadIdx.x;
    if (m >= M) return;
    int r0 = blockIdx.y * rows_per;
    int r1 = r0 + rows_per;
    if (r1 > nblk) r1 = nblk;
    if (r0 >= r1) return;
    float s0 = 0.f, s1 = 0.f, s2 = 0.f, s3 = 0.f;
    int r = r0;
    for (; r + 3 < r1; r += 4) {
        s0 += partials[(size_t)(r + 0) * M + m];
        s1 += partials[(size_t)(r + 1) * M + m];
        s2 += partials[(size_t)(r + 2) * M + m];
        s3 += partials[(size_t)(r + 3) * M + m];
    }
    for (; r < r1; ++r) s0 += partials[(size_t)r * M + m];
    atomicAdd(&out[m], (s0 + s1) + (s2 + s3));
}

extern "C" void kernel_launch(void* const* d_in, const int* in_sizes, int n_in,
                              void* d_out, int out_size, void* d_ws, size_t ws_size,
                              hipStream_t stream)
{
    const int*   elem  = (const int*)d_in[0];
    const int*   nbr   = (const int*)d_in[1];
    const float* dist  = (const float*)d_in[2];
    const float* y_ab  = (const float*)d_in[3];
    const float* sa_ab = (const float*)d_in[4];
    const float* kr_ab = (const float*)d_in[5];
    float* out = (float*)d_out;

    const int natoms = in_sizes[0];
    const long long P = (long long)in_sizes[2];
    const int M = out_size;
    const int A = natoms / M;
    int ashift = -1;
    if (A > 0 && (A & (A - 1)) == 0) {
        int s = 0;
        while ((1 << s) < A) ++s;
        ashift = s;
    }
    const int nwords = (natoms + 15) / 16;

    // workspace layout: [packed: nwords u32 (256B aligned)][partials: nblk*M f32]
    size_t packed_bytes = ((size_t)nwords * 4 + 255) & ~(size_t)255;
    bool have_packed = (ws_size >= packed_bytes);
    unsigned* packed = have_packed ? (unsigned*)d_ws : nullptr;
    if (!have_packed) return;  // harness always provides workspace

    const int BLOCK = 1024;
    int nblk = 512;            // 2 blocks/CU on 256 CUs -> 32 waves/CU
    float* partials = nullptr;
    int mode = 1;              // global-atomic fallback
    {
        size_t avail = ws_size - packed_bytes;
        size_t rowb = (size_t)M * 4;
        long long maxrows = (long long)(avail / rowb);
        if (maxrows >= 64) {
            nblk = (int)(maxrows < 512 ? maxrows : 512);
            partials = (float*)((char*)d_ws + packed_bytes);
            mode = 0;
        }
    }

    // kernel 1: pack + zero out
    {
        int total = (nwords > M) ? nwords : M;
        int g = (total + 255) / 256;
        hipLaunchKernelGGL(pack_zero_kernel, dim3(g), dim3(256), 0, stream,
                           elem, natoms, nwords, packed, out, M);
    }

    // kernel 2: main
    {
        size_t smem = (size_t)M * 4 + 16 * sizeof(float2) + (size_t)nwords * 4;
        hipLaunchKernelGGL(rep_main_kernel, dim3(nblk), dim3(BLOCK), smem, stream,
                           nbr, dist, packed, y_ab, sa_ab, kr_ab,
                           P, M, nwords, ashift, A, partials, out, mode);
    }

    // kernel 3: reduce partial rows
    if (mode == 0) {
        const int SPLIT = 32;
        int rows_per = (nblk + SPLIT - 1) / SPLIT;
        dim3 grid((M + 255) / 256, SPLIT);
        hipLaunchKernelGGL(reduce_kernel, grid, dim3(256), 0, stream,
                           partials, out, M, nblk, rows_per);
    }
}

// Round 2
// 158.350 us; speedup vs baseline: 1.0039x; 1.0039x over previous
//
#include <hip/hip_runtime.h>

// RepulsionXTB: per-pair repulsion energy, segment-summed per molecule.
//
// Inputs (setup_inputs order, harness converts ints to int32):
//   d_in[0] element_idxs  int32  [M*A]   (M=2048, A=64 -> 131072)
//   d_in[1] neighbor_idxs int32  [2*P]   (P=8388608)
//   d_in[2] distances     f32    [P]
//   d_in[3] y_ab          f32    [16]
//   d_in[4] sqrt_alpha_ab f32    [16]
//   d_in[5] k_rep_ab      f32    [16]   (1.5 everywhere except [0,0]=1.0)
// Output: energies f32 [M]
//
// R5 notes: R4's source-level phasing was re-serialized by the scheduler
// (VGPR=28 proves it; needs >=40 live for real 8-wide phases). This round
// pins the phases with sched_barrier(0) fences so the 16 pk reads and the
// 8 tbl reads each issue as one batch (2 batched LDS waits per 8 pairs
// instead of 8 serial depth-2 chains). 8-pair groups come from two
// grid-stride positions (q, q+gstride) -> every load stays fully
// coalesced (R4's q<<1 pattern was stride-32B, half-coalesced).
// mol = floor(a0/A) via exact magic multiply (natoms < 2^21), branch-free.

#define AB_D 1.8897261258369282
#define L2E  1.4426950408889634f   // log2(e)

// ---------------- kernel 1: pack species to 2 bits/atom + zero output -------
__global__ __launch_bounds__(256) void pack_zero_kernel(
    const int* __restrict__ elem, int natoms, int nwords,
    unsigned* __restrict__ packed, float* __restrict__ out, int M)
{
    int g = blockIdx.x * blockDim.x + threadIdx.x;
    if (g < M) out[g] = 0.0f;
    if (packed != nullptr && g < nwords) {
        int base = g * 16;
        unsigned w = 0u;
        if (base + 16 <= natoms) {
            const int4* p = (const int4*)(elem + base);
            #pragma unroll
            for (int q = 0; q < 4; ++q) {
                int4 v = p[q];
                w |= ((unsigned)v.x & 3u) << (2 * (4 * q + 0));
                w |= ((unsigned)v.y & 3u) << (2 * (4 * q + 1));
                w |= ((unsigned)v.z & 3u) << (2 * (4 * q + 2));
                w |= ((unsigned)v.w & 3u) << (2 * (4 * q + 3));
            }
        } else {
            for (int j = 0; j < 16; ++j) {
                int a = base + j;
                unsigned s = (a < natoms) ? ((unsigned)elem[a] & 3u) : 0u;
                w |= s << (2 * j);
            }
        }
        packed[g] = w;
    }
}

// ---------------- kernel 2: main pair loop ----------------------------------
// LDS layout: [acc: M f32][tbl: 16 float2][pk: nwords u32]
__global__ __launch_bounds__(1024, 8) void rep_main_kernel(
    const int* __restrict__ nbr, const float* __restrict__ dist,
    const unsigned* __restrict__ packed_g,
    const float* __restrict__ y_ab, const float* __restrict__ sa_ab,
    const float* __restrict__ kr_ab,
    long long P, int M, int nwords, unsigned long long molMagic, int A,
    float* __restrict__ partials, float* __restrict__ out,
    int mode /*0 = write partial row, 1 = global atomics*/)
{
    extern __shared__ char smem[];
    float*  acc = (float*)smem;
    float2* tbl = (float2*)(smem + (size_t)M * 4);
    unsigned* pk = (unsigned*)(smem + (size_t)M * 4 + 16 * sizeof(float2));

    const int tid = threadIdx.x;
    const int nthr = blockDim.x;

    for (int m = tid; m < M; m += nthr) acc[m] = 0.0f;
    for (int w = tid; w < nwords; w += nthr) pk[w] = packed_g[w];
    if (tid < 16) {
        float sa = sa_ab[tid] * L2E;           // pre-scale for exp2
        if (kr_ab[tid] == 1.0f) sa = -sa;      // sign bit encodes kr==1 (H-H)
        tbl[tid] = make_float2(y_ab[tid], sa);
    }
    __syncthreads();

    const float ABf   = (float)AB_D;
    const float DMIN  = (float)(1e-7 * AB_D);
    const float RCINV = (float)(1.0 / (5.2 * AB_D));

    const int4*   nb04 = (const int4*)nbr;
    const int4*   nb14 = (const int4*)(nbr + P);
    const float4* dv4  = (const float4*)dist;

    long long P4 = P >> 2;
    long long gstride = (long long)gridDim.x * nthr;
    long long i = (long long)blockIdx.x * nthr + tid;

    // -------- main loop: 8 pairs = two coalesced int4-groups per iteration --
    for (; i + gstride < P4; i += 2 * gstride) {
        long long qa = i, qb = i + gstride;
        // phase 0: 6 x 16B global loads (independent, fully coalesced)
        int4   i0a = nb04[qa];    int4   i0b = nb04[qb];
        int4   i1a = nb14[qa];    int4   i1b = nb14[qb];
        float4 da  = dv4[qa];     float4 db  = dv4[qb];

        unsigned a0[8] = {(unsigned)i0a.x,(unsigned)i0a.y,(unsigned)i0a.z,(unsigned)i0a.w,
                          (unsigned)i0b.x,(unsigned)i0b.y,(unsigned)i0b.z,(unsigned)i0b.w};
        unsigned a1[8] = {(unsigned)i1a.x,(unsigned)i1a.y,(unsigned)i1a.z,(unsigned)i1a.w,
                          (unsigned)i1b.x,(unsigned)i1b.y,(unsigned)i1b.z,(unsigned)i1b.w};
        float dr[8] = {da.x,da.y,da.z,da.w, db.x,db.y,db.z,db.w};

        // phase 1: 16 species-word LDS reads, issued as one batch
        unsigned w0[8], w1[8];
        #pragma unroll
        for (int j = 0; j < 8; ++j) {
            w0[j] = pk[a0[j] >> 4];
            w1[j] = pk[a1[j] >> 4];
        }
        __builtin_amdgcn_sched_barrier(0);   // pin: no consumer moves above

        // phase 2: 8 pair-table LDS reads as one batch; mol via magic divide
        float2   t[8];
        unsigned mol[8];
        #pragma unroll
        for (int j = 0; j < 8; ++j) {
            unsigned s0 = (w0[j] >> ((a0[j] & 15u) * 2u)) & 3u;
            unsigned s1 = (w1[j] >> ((a1[j] & 15u) * 2u)) & 3u;
            t[j] = tbl[s0 * 4u + s1];
            mol[j] = (unsigned)(((unsigned long long)a0[j] * molMagic) >> 42);
        }
        __builtin_amdgcn_sched_barrier(0);   // pin: VALU stays below reads

        // phase 3: pure VALU, branchless (outside cutoff -> exp2(-inf) = 0)
        float rep[8];
        #pragma unroll
        for (int j = 0; j < 8; ++j) {
            float d   = fmaxf(dr[j] * ABf, DMIN);
            float x   = d * RCINV;
            float om  = fmaxf(fmaf(-x, x, 1.0f), 0.0f); // 0 outside cutoff
            float r   = __builtin_amdgcn_rcpf(om);      // +inf outside
            float e   = fmaf(-L2E, r, L2E);             // -inf outside
            float sq  = __builtin_amdgcn_sqrtf(d);
            float fac = (t[j].y < 0.0f) ? 1.0f : sq;    // kr==1 ? d : d^1.5
            float arg = fmaf(-fabsf(t[j].y), d * fac, e);
            float ex  = __builtin_amdgcn_exp2f(arg);
            rep[j] = t[j].x * __builtin_amdgcn_rcpf(d) * ex;
        }

        // phase 4: LDS atomics (fire-and-forget; may overlap next iter loads)
        #pragma unroll
        for (int j = 0; j < 8; ++j)
            atomicAdd(&acc[mol[j]], rep[j]);
    }

    // leftover single int4-groups (at most when grid doesn't divide P4)
    for (; i < P4; i += gstride) {
        int4   i0 = nb04[i];
        int4   i1 = nb14[i];
        float4 dv = dv4[i];
        unsigned a0[4] = {(unsigned)i0.x,(unsigned)i0.y,(unsigned)i0.z,(unsigned)i0.w};
        unsigned a1[4] = {(unsigned)i1.x,(unsigned)i1.y,(unsigned)i1.z,(unsigned)i1.w};
        float dr[4] = {dv.x,dv.y,dv.z,dv.w};
        #pragma unroll
        for (int j = 0; j < 4; ++j) {
            unsigned s0 = (pk[a0[j] >> 4] >> ((a0[j] & 15u) * 2u)) & 3u;
            unsigned s1 = (pk[a1[j] >> 4] >> ((a1[j] & 15u) * 2u)) & 3u;
            float2 t = tbl[s0 * 4u + s1];
            float d   = fmaxf(dr[j] * ABf, DMIN);
            float x   = d * RCINV;
            float om  = fmaxf(fmaf(-x, x, 1.0f), 0.0f);
            float r   = __builtin_amdgcn_rcpf(om);
            float e   = fmaf(-L2E, r, L2E);
            float sq  = __builtin_amdgcn_sqrtf(d);
            float fac = (t.y < 0.0f) ? 1.0f : sq;
            float arg = fmaf(-fabsf(t.y), d * fac, e);
            float ex  = __builtin_amdgcn_exp2f(arg);
            float rep = t.x * __builtin_amdgcn_rcpf(d) * ex;
            unsigned mol = (unsigned)(((unsigned long long)a0[j] * molMagic) >> 42);
            atomicAdd(&acc[mol], rep);
        }
    }

    // tail (P not divisible by 4) — handled by block 0 (empty for P=8.4M)
    long long tail0 = P4 << 2;
    if (blockIdx.x == 0) {
        const int* nb0 = nbr;
        const int* nb1 = nbr + P;
        for (long long p = tail0 + tid; p < P; p += nthr) {
            unsigned ua0 = (unsigned)nb0[p], ua1 = (unsigned)nb1[p];
            float d = fmaxf(dist[p] * ABf, DMIN);
            unsigned s0 = (pk[ua0 >> 4] >> ((ua0 & 15u) * 2u)) & 3u;
            unsigned s1 = (pk[ua1 >> 4] >> ((ua1 & 15u) * 2u)) & 3u;
            float2 t = tbl[s0 * 4u + s1];
            float x   = d * RCINV;
            float om  = fmaxf(fmaf(-x, x, 1.0f), 0.0f);
            float r   = __builtin_amdgcn_rcpf(om);
            float e   = fmaf(-L2E, r, L2E);
            float sq  = __builtin_amdgcn_sqrtf(d);
            float fac = (t.y < 0.0f) ? 1.0f : sq;
            float arg = fmaf(-fabsf(t.y), d * fac, e);
            float ex  = __builtin_amdgcn_exp2f(arg);
            float rep = t.x * __builtin_amdgcn_rcpf(d) * ex;
            unsigned mol = (unsigned)(((unsigned long long)ua0 * molMagic) >> 42);
            atomicAdd(&acc[mol], rep);
        }
    }
    __syncthreads();

    if (mode == 0) {
        float* row = partials + (size_t)blockIdx.x * (size_t)M;
        for (int m = tid; m < M; m += nthr) row[m] = acc[m];
    } else {
        for (int m = tid; m < M; m += nthr) {
            float v = acc[m];
            if (v != 0.0f) atomicAdd(&out[m], v);
        }
    }
}

// ---------------- kernel 3: column-sum the partial rows ---------------------
__global__ __launch_bounds__(256) void reduce_kernel(
    const float* __restrict__ partials, float* __restrict__ out,
    int M, int nblk, int rows_per)
{
    int m = blockIdx.x * blockDim.x + threadIdx.x;
    if (m >= M) return;
    int r0 = blockIdx.y * rows_per;
    int r1 = r0 + rows_per;
    if (r1 > nblk) r1 = nblk;
    if (r0 >= r1) return;
    float s0 = 0.f, s1 = 0.f, s2 = 0.f, s3 = 0.f;
    int r = r0;
    for (; r + 3 < r1; r += 4) {
        s0 += partials[(size_t)(r + 0) * M + m];
        s1 += partials[(size_t)(r + 1) * M + m];
        s2 += partials[(size_t)(r + 2) * M + m];
        s3 += partials[(size_t)(r + 3) * M + m];
    }
    for (; r < r1; ++r) s0 += partials[(size_t)r * M + m];
    atomicAdd(&out[m], (s0 + s1) + (s2 + s3));
}

extern "C" void kernel_launch(void* const* d_in, const int* in_sizes, int n_in,
                              void* d_out, int out_size, void* d_ws, size_t ws_size,
                              hipStream_t stream)
{
    const int*   elem  = (const int*)d_in[0];
    const int*   nbr   = (const int*)d_in[1];
    const float* dist  = (const float*)d_in[2];
    const float* y_ab  = (const float*)d_in[3];
    const float* sa_ab = (const float*)d_in[4];
    const float* kr_ab = (const float*)d_in[5];
    float* out = (float*)d_out;

    const int natoms = in_sizes[0];
    const long long P = (long long)in_sizes[2];
    const int M = out_size;
    const int A = natoms / M;
    // exact floor(a0/A) for a0 < 2^21 via magic multiply: M = ceil(2^42/A)
    unsigned long long molMagic =
        (A > 0) ? ((((unsigned long long)1 << 42) + (unsigned long long)A - 1)
                   / (unsigned long long)A)
                : 1ull;
    const int nwords = (natoms + 15) / 16;

    // workspace layout: [packed: nwords u32 (256B aligned)][partials: nblk*M f32]
    size_t packed_bytes = ((size_t)nwords * 4 + 255) & ~(size_t)255;
    bool have_packed = (ws_size >= packed_bytes);
    unsigned* packed = have_packed ? (unsigned*)d_ws : nullptr;
    if (!have_packed) return;  // harness always provides workspace

    const int BLOCK = 1024;
    int nblk = 512;            // 2 blocks/CU on 256 CUs -> 32 waves/CU
    float* partials = nullptr;
    int mode = 1;              // global-atomic fallback
    {
        size_t avail = ws_size - packed_bytes;
        size_t rowb = (size_t)M * 4;
        long long maxrows = (long long)(avail / rowb);
        if (maxrows >= 64) {
            nblk = (int)(maxrows < 512 ? maxrows : 512);
            partials = (float*)((char*)d_ws + packed_bytes);
            mode = 0;
        }
    }

    // kernel 1: pack + zero out
    {
        int total = (nwords > M) ? nwords : M;
        int g = (total + 255) / 256;
        hipLaunchKernelGGL(pack_zero_kernel, dim3(g), dim3(256), 0, stream,
                           elem, natoms, nwords, packed, out, M);
    }

    // kernel 2: main
    {
        size_t smem = (size_t)M * 4 + 16 * sizeof(float2) + (size_t)nwords * 4;
        hipLaunchKernelGGL(rep_main_kernel, dim3(nblk), dim3(BLOCK), smem, stream,
                           nbr, dist, packed, y_ab, sa_ab, kr_ab,
                           P, M, nwords, molMagic, A, partials, out, mode);
    }

    // kernel 3: reduce partial rows
    if (mode == 0) {
        const int SPLIT = 32;
        int rows_per = (nblk + SPLIT - 1) / SPLIT;
        dim3 grid((M + 255) / 256, SPLIT);
        hipLaunchKernelGGL(reduce_kernel, grid, dim3(256), 0, stream,
                           partials, out, M, nblk, rows_per);
    }
}